// Round 5
// baseline (379.790 us; speedup 1.0000x reference)
//
#include <hip/hip_runtime.h>
#include <stdint.h>

#define D_MODEL 1024
#define D_STATE 16
#define D_INNER 2048
#define BATCH   4
#define SEQ     2048
#define ML      (BATCH*SEQ)   // 8192 rows
#define CH      64
#define NCHUNK  (SEQ/CH)      // 32
#define KSEG    8             // K-split for B/C projection GEMM

typedef unsigned short u16;
typedef u16   u16x8  __attribute__((ext_vector_type(8)));
typedef short s16x8  __attribute__((ext_vector_type(8)));
typedef float f32x4  __attribute__((ext_vector_type(4)));

__device__ __forceinline__ float b2f(u16 u){
  union { uint32_t i; float f; } v; v.i = ((uint32_t)u) << 16; return v.f;
}
__device__ __forceinline__ u16 f2b(float f){
  uint32_t x = __float_as_uint(f);
  return (u16)((x + 0x7fffu + ((x >> 16) & 1u)) >> 16);   // RNE
}
__device__ __forceinline__ float silu_f(float v){
  return v / (1.f + __expf(-v));
}
// async global->LDS, 16 B per lane; lds base must be wave-uniform (lane i lands at base + i*16)
__device__ __forceinline__ void gl_lds16(const void* gp, void* lp){
  __builtin_amdgcn_global_load_lds(
      (const __attribute__((address_space(1))) void*)gp,
      (__attribute__((address_space(3))) void*)lp, 16, 0, 0);
}

// ------------- transpose + cast: in f32 (R x C) -> out bf16 (C x R) -------------
__global__ __launch_bounds__(256) void transpose_cast_k(const float* __restrict__ in,
                                                        u16* __restrict__ out,
                                                        int R, int C){
  __shared__ float tile[32][33];
  int bx = blockIdx.x * 32, by = blockIdx.y * 32;
  int tx = threadIdx.x & 31, ty = threadIdx.x >> 5;
  #pragma unroll
  for (int i = 0; i < 32; i += 8)
    tile[ty + i][tx] = in[(size_t)(by + ty + i) * C + bx + tx];
  __syncthreads();
  #pragma unroll
  for (int i = 0; i < 32; i += 8)
    out[(size_t)(bx + ty + i) * R + by + tx] = f2b(tile[tx][ty + i]);
}

// ------------- elementwise cast f32 -> bf16 (8 per thread) -------------
__global__ __launch_bounds__(256) void cast_k(const float* __restrict__ in,
                                              u16* __restrict__ out){
  size_t i = ((size_t)blockIdx.x * 256 + threadIdx.x) * 8;
  f32x4 a = *(const f32x4*)(in + i);
  f32x4 b = *(const f32x4*)(in + i + 4);
  u16x8 o;
  #pragma unroll
  for (int j = 0; j < 4; ++j){ o[j] = f2b(a[j]); o[4+j] = f2b(b[j]); }
  *(u16x8*)(out + i) = o;
}

// ------------- W_B|W_C (2048x16 f32 each) -> Wt_bc bf16 32x2048 -------------
__global__ __launch_bounds__(256) void bc_wt_k(const float* __restrict__ W_B,
                                               const float* __restrict__ W_C,
                                               u16* __restrict__ Wt){
  int n = blockIdx.y;                          // 0..31
  int k = blockIdx.x * 256 + threadIdx.x;      // 0..2047
  const float* src = (n < 16) ? W_B : W_C;
  Wt[(size_t)n * D_INNER + k] = f2b(src[(size_t)k * 16 + (n & 15)]);
}

// ================= 2-phase 256x256 GEMM for in_proj (fragment-major LDS) =================
// M=8192, N=4096, K=1024. 512 threads = 8 waves (2M x 4N), per-wave output 128x64.
// FRAGMENT-MAJOR LDS: each MFMA fragment-group (16 rows x 8 k) is one contiguous 1KB
// block staged by a single gl_lds16; every ds_read_b128 is base + lane*16B -> 0 conflicts
// (verified R4: SQ_LDS_BANK_CONFLICT = 0). R4 showed the 8-barrier/tile schedule is
// sync-bound (MfmaUtil 27%, 1 block/CU) -> collapse to 2 barriers/tile, 2 MFMA runs of
// 32, counted lgkm so reads retire under MFMA.
// RACE RULES: (1) vmcnt drains only OWN DMAs -> cross-wave LDS reads of DMA'd data sit
// after {every wave drained + s_barrier}. (2) every stage-over-slot is separated from all
// waves' last-read drain point by a barrier. Ledger audited per hazard below.
#define G1_K  1024
#define G1_NT (G1_K/64)   // 16 K-tiles

__global__ __launch_bounds__(512, 2) void gemm1_k(const u16* __restrict__ A,
                                                  const u16* __restrict__ Bt,
                                                  const float* __restrict__ bias,
                                                  u16* __restrict__ out0,
                                                  u16* __restrict__ out1){
  __shared__ __align__(16) u16 ldsAll[256*264];  // 135168 B; staging uses first 128 KB,
  u16* ldsA = ldsAll;                            // epilogue reuses full array (pad 264)
  u16* ldsB = ldsAll + 4*8192;

  const int bid = blockIdx.x;
  const int xcd = bid & 7, t2 = bid >> 3;
  const int n0 = (xcd*2 + (t2 & 1)) * 256;     // 16 n-blocks, 2 per XCD
  const int m0 = (t2 >> 1) * 256;              // 32 m-blocks

  const int tid  = threadIdx.x;
  const int wave = tid >> 6, lane = tid & 63;
  const int wr = wave >> 2;                    // 0..1: M half
  const int wc = wave & 3;                     // 0..3: N quarter
  const int lrow = lane & 15;
  const int q    = lane >> 4;                  // 0..3

  // staging: one gl_lds16 = one 1KB fragment-group (lane i -> row i&15, kchunk i>>4)
  auto stageA = [&](int buf, int h, int k0){
    const u16* s = A + (size_t)(m0 + h*128 + wave*16 + lrow) * G1_K + k0 + q*8;
    u16* d = ldsA + (buf*2 + h)*8192 + wave*1024;
    gl_lds16(s,      d);        // kk=0 group
    gl_lds16(s + 32, d + 512);  // kk=1 group
  };
  auto stageB = [&](int buf, int h, int k0){
    const u16* s = Bt + (size_t)(n0 + h*128 + wave*16 + lrow) * G1_K + k0 + q*8;
    u16* d = ldsB + (buf*2 + h)*8192 + wave*1024;
    gl_lds16(s,      d);
    gl_lds16(s + 32, d + 512);
  };

  // fragment read bases (u16 units); frag(group g, kk) at base + g*1024 + kk*512 + lane*8
  const u16* aRd0 = ldsA + wr*8192 + (size_t)lane*8;                    // + buf*16384 + mi*1024 + kk*512
  const u16* bRd0 = ldsB + (wc>>1)*8192 + (wc&1)*4096 + (size_t)lane*8; // + buf*16384 + nj*1024 + kk*512

  f32x4 acc[8][4];
  #pragma unroll
  for (int i = 0; i < 8; ++i)
    #pragma unroll
    for (int j = 0; j < 4; ++j) acc[i][j] = (f32x4){0.f,0.f,0.f,0.f};

  s16x8 aA[2][2], aB[2][2];       // alternating A-quadrant frags (reused via in-order issue)
  s16x8 bX[4][2], bY[4][2];       // alternating per-tile B frags

  #define READ_AQ(dst, Q, nb)                                            \
    { const u16* p_ = aRd0 + (nb)*16384 + (Q)*2048;                      \
      dst[0][0] = *(const s16x8*)(p_);                                   \
      dst[0][1] = *(const s16x8*)(p_ + 512);                             \
      dst[1][0] = *(const s16x8*)(p_ + 1024);                            \
      dst[1][1] = *(const s16x8*)(p_ + 1536); }
  #define READ_B8(dst, nb)                                               \
    { const u16* p_ = bRd0 + (nb)*16384;                                 \
      _Pragma("unroll")                                                  \
      for (int nj_ = 0; nj_ < 4; ++nj_){                                 \
        dst[nj_][0] = *(const s16x8*)(p_ + nj_*1024);                    \
        dst[nj_][1] = *(const s16x8*)(p_ + nj_*1024 + 512); } }
  // kk-outer: dependent same-acc MFMAs sit 8 apart (was 2)
  #define MFMA_Q(Q, AF, BF)                                              \
    { _Pragma("unroll")                                                  \
      for (int kk_ = 0; kk_ < 2; ++kk_){                                 \
        _Pragma("unroll")                                                \
        for (int nj_ = 0; nj_ < 4; ++nj_){                               \
          acc[2*(Q)][nj_]   = __builtin_amdgcn_mfma_f32_16x16x32_bf16(AF[0][kk_], BF[nj_][kk_], acc[2*(Q)][nj_],   0,0,0); \
          acc[2*(Q)+1][nj_] = __builtin_amdgcn_mfma_f32_16x16x32_bf16(AF[1][kk_], BF[nj_][kk_], acc[2*(Q)+1][nj_], 0,0,0); } } }

  // ---- prologue: stage tile0 + B(t1); drain tile0 (own) + barrier; cross-wave reads ----
  stageA(0,0,0); stageA(0,1,0); stageB(0,0,0); stageB(0,1,0);
  stageB(1,0,64); stageB(1,1,64);
  asm volatile("s_waitcnt vmcnt(4)" ::: "memory");   // own A0,B0 done; B1 in flight
  __builtin_amdgcn_s_barrier();                      // all waves' A0,B0 visible
  __builtin_amdgcn_sched_barrier(0);
  READ_B8(bX, 0);
  READ_AQ(aA, 0, 0);

  auto tile_body = [&](int tt, int buf, s16x8 (&bC)[4][2], s16x8 (&bN)[4][2]){
    const int k1 = (tt+1 < G1_NT ? tt+1 : G1_NT-1) * 64;   // clamped: junk restage/read, never used
    const int k2 = (tt+2 < G1_NT ? tt+2 : G1_NT-1) * 64;
    const int nb = buf ^ 1;

    // ======== P0: stage A(t+1); read Q1; MFMA Q0, Q1 ========
    // stage A(t+1) over A(t-1): A(t-1) last reads (AQ3) drained at P1(t-1) lgkm(8),
    // barrier S3(t-1) separates -> safe.
    stageA(nb, 0, k1);
    stageA(nb, 1, k1);
    READ_AQ(aB, 1, buf);
    // outstanding lgkm: B8(t)[<=8] + AQ0(t)[4] + AQ1[4]; lgkm(4) -> B8(t)+AQ0 done
    asm volatile("s_waitcnt lgkmcnt(4)" ::: "memory");
    __builtin_amdgcn_sched_barrier(0);
    __builtin_amdgcn_s_setprio(1);
    MFMA_Q(0, aA, bC);
    __builtin_amdgcn_s_setprio(0);
    asm volatile("s_waitcnt lgkmcnt(0)" ::: "memory");   // AQ1 done
    __builtin_amdgcn_sched_barrier(0);
    __builtin_amdgcn_s_setprio(1);
    MFMA_Q(1, aB, bC);
    __builtin_amdgcn_s_setprio(0);

    // ======== P1: read Q2,Q3; publish t+1; read B8/Q0(t+1); stage B(t+2); MFMA Q2, Q3 ====
    READ_AQ(aA, 2, buf);     // aA free: Q0 consumed at MFMA issue (in-order)
    READ_AQ(aB, 3, buf);     // aB free: Q1 consumed
    asm volatile("s_waitcnt vmcnt(0)" ::: "memory");   // own A(t+1) (and older B(t+1)) done
    __builtin_amdgcn_s_barrier();                      // S2: all waves' t+1 DMAs visible
    __builtin_amdgcn_sched_barrier(0);
    READ_B8(bN, nb);
    // stage B(t+2) over B(t): B(t) reads (B8 at P1(t-1)) drained at each wave's P0(t)
    // lgkm(4); every wave passed S2 after that drain -> safe.
    stageB(buf, 0, k2);
    stageB(buf, 1, k2);
    // outstanding lgkm: AQ2[4] + AQ3[4] + B8(t+1)[8]; lgkm(12) -> AQ2 done
    asm volatile("s_waitcnt lgkmcnt(12)" ::: "memory");
    __builtin_amdgcn_sched_barrier(0);
    __builtin_amdgcn_s_setprio(1);
    MFMA_Q(2, aA, bC);
    __builtin_amdgcn_s_setprio(0);
    asm volatile("s_waitcnt lgkmcnt(8)" ::: "memory");   // AQ3 done; B8(t+1) may stay out
    __builtin_amdgcn_sched_barrier(0);
    READ_AQ(aA, 0, nb);      // Q0 of t+1; aA free: Q2 consumed; retires under Q3
    __builtin_amdgcn_s_setprio(1);
    MFMA_Q(3, aB, bC);
    __builtin_amdgcn_s_setprio(0);
    __builtin_amdgcn_s_barrier();                      // S3: end of tile
  };

  for (int tt2 = 0; tt2 < G1_NT; tt2 += 2) {
    tile_body(tt2,     0, bX, bY);
    tile_body(tt2 + 1, 1, bY, bX);
  }

  // ---- epilogue: drain junk DMA, restage C through LDS (pad 264), coalesced stores ----
  asm volatile("s_waitcnt vmcnt(0)" ::: "memory");
  __syncthreads();

  #pragma unroll
  for (int nj = 0; nj < 4; ++nj) {
    const int colg = n0 + wc*64 + nj*16 + lrow;
    const float bv = bias[colg];
    const int coll = wc*64 + nj*16 + lrow;
    #pragma unroll
    for (int mi = 0; mi < 8; ++mi) {
      #pragma unroll
      for (int r = 0; r < 4; ++r) {
        const int rowl = wr*128 + mi*16 + q*4 + r;   // C/D: col=lane&15, row=quad*4+reg
        ldsAll[rowl*264 + coll] = f2b(silu_f(acc[mi][nj][r] + bv));
      }
    }
  }
  __syncthreads();

  u16* op = (n0 < D_INNER) ? out0 : out1;
  const int colbase = n0 & (D_INNER - 1);
  #pragma unroll
  for (int it = 0; it < 16; ++it) {
    const int f   = it*512 + tid;
    const int row = f >> 5;           // 0..255
    const int ch  = f & 31;           // 16B chunk within 512B row-span
    u16x8 v = *(const u16x8*)(ldsAll + row*264 + ch*8);
    *(u16x8*)(op + (size_t)(m0 + row)*D_INNER + colbase + ch*8) = v;
  }
  #undef READ_AQ
  #undef READ_B8
  #undef MFMA_Q
}

// ------------- MFMA GEMM, double-buffered DMA, 1 barrier/iter (kept for gemm2) -------------
// MODE 0: outf[row*N+col] = f32(acc + bias[col])          (final output, f32)
template<int MODE>
__global__ __launch_bounds__(256) void gemm_bt(const u16* __restrict__ A,
                                               const u16* __restrict__ Bt,
                                               const float* __restrict__ bias,
                                               u16* __restrict__ out0,
                                               u16* __restrict__ out1,
                                               float* __restrict__ outf,
                                               int M, int N, int K, int n_per_xcd){
  __shared__ __align__(16) u16 Asb[2][128*32];   // unpadded: DMA layout constraint
  __shared__ __align__(16) u16 Bsb[2][128*32];
  const int bid = blockIdx.x;
  const int xcd = bid & 7, t2 = bid >> 3;
  const int n0 = (xcd * n_per_xcd + (t2 % n_per_xcd)) * 128;
  const int m0 = (t2 / n_per_xcd) * 128;
  const int t    = threadIdx.x;
  const int wave = t >> 6, lane = t & 63;
  const int wm   = (wave >> 1) * 64, wn = (wave & 1) * 64;
  const int lrow = lane & 15, kq = (lane >> 4) * 8;
  const int srow = lane >> 2;            // staging: row within 16-row block
  const int scol = (lane & 3) * 8;       // staging: 8-u16 chunk within row

  f32x4 acc[4][4];
  #pragma unroll
  for (int i = 0; i < 4; ++i)
    #pragma unroll
    for (int j = 0; j < 4; ++j)
      acc[i][j] = (f32x4){0.f, 0.f, 0.f, 0.f};

  auto stage = [&](int buf, int k0){
    #pragma unroll
    for (int i = 0; i < 2; ++i) {
      int R0 = (wave*2 + i) * 16;        // 0,16,...,112
      gl_lds16(&A [(size_t)(m0 + R0 + srow)*K + k0 + scol], &Asb[buf][R0*32]);
      gl_lds16(&Bt[(size_t)(n0 + R0 + srow)*K + k0 + scol], &Bsb[buf][R0*32]);
    }
  };

  const int KT = K >> 5;
  stage(0, 0);
  __syncthreads();
  for (int kt = 0; kt < KT; ++kt) {
    const int cur = kt & 1;
    if (kt + 1 < KT) stage(1 - cur, (kt + 1) * 32);   // prefetch overlaps compute below
    s16x8 af[4], bfr[4];
    #pragma unroll
    for (int i = 0; i < 4; ++i) af[i]  = *(const s16x8*)&Asb[cur][(wm + i*16 + lrow)*32 + kq];
    #pragma unroll
    for (int j = 0; j < 4; ++j) bfr[j] = *(const s16x8*)&Bsb[cur][(wn + j*16 + lrow)*32 + kq];
    #pragma unroll
    for (int i = 0; i < 4; ++i)
      #pragma unroll
      for (int j = 0; j < 4; ++j)
        acc[i][j] = __builtin_amdgcn_mfma_f32_16x16x32_bf16(af[i], bfr[j], acc[i][j], 0, 0, 0);
    __syncthreads();   // drains prefetch DMA + protects cur buffer reuse
  }

  const int Nh = N >> 1;
  #pragma unroll
  for (int i = 0; i < 4; ++i) {
    #pragma unroll
    for (int j = 0; j < 4; ++j) {
      int col = n0 + wn + j*16 + lrow;
      float bv = bias[col];
      #pragma unroll
      for (int r = 0; r < 4; ++r) {
        int row = m0 + wm + i*16 + (lane >> 4)*4 + r;   // C/D: col=lane&15, row=quad*4+reg
        float v = acc[i][j][r] + bv;
        if (MODE == 0) {
          outf[(size_t)row * N + col] = v;
        } else {
          float s = silu_f(v);
          if (col < Nh) out0[(size_t)row * Nh + col]        = f2b(s);
          else          out1[(size_t)row * Nh + (col - Nh)] = f2b(s);
        }
      }
    }
  }
}

// ------------- depthwise conv(3) only -------------
__global__ __launch_bounds__(256) void conv_k(const u16* __restrict__ xs,
    const float* __restrict__ conv_w, const float* __restrict__ conv_b,
    u16* __restrict__ xconv){
  int bl = blockIdx.x;
  int l = bl & (SEQ-1);
  int d = threadIdx.x * 8;
  const u16* row0 = xs + (size_t)bl * D_INNER + d;

  float f0[8], fm[8], fp[8];
  { u16x8 v = *(const u16x8*)row0;
    #pragma unroll
    for (int j = 0; j < 8; ++j) f0[j] = b2f(v[j]); }
  if (l > 0) {
    u16x8 v = *(const u16x8*)(row0 - D_INNER);
    #pragma unroll
    for (int j = 0; j < 8; ++j) fm[j] = b2f(v[j]);
  } else {
    #pragma unroll
    for (int j = 0; j < 8; ++j) fm[j] = 0.f;
  }
  if (l < SEQ-1) {
    u16x8 v = *(const u16x8*)(row0 + D_INNER);
    #pragma unroll
    for (int j = 0; j < 8; ++j) fp[j] = b2f(v[j]);
  } else {
    #pragma unroll
    for (int j = 0; j < 8; ++j) fp[j] = 0.f;
  }

  const float* wp = conv_w + (size_t)d * 3;
  float wl[24];
  #pragma unroll
  for (int q = 0; q < 6; ++q){
    f32x4 v = *(const f32x4*)(wp + q*4);
    #pragma unroll
    for (int j = 0; j < 4; ++j) wl[q*4 + j] = v[j];
  }
  float cb[8];
  { f32x4 c0 = *(const f32x4*)(conv_b + d), c1 = *(const f32x4*)(conv_b + d + 4);
    #pragma unroll
    for (int j = 0; j < 4; ++j){ cb[j] = c0[j]; cb[4+j] = c1[j]; } }

  u16x8 o;
  #pragma unroll
  for (int j = 0; j < 8; ++j)
    o[j] = f2b(wl[3*j]*fm[j] + wl[3*j+1]*f0[j] + wl[3*j+2]*fp[j] + cb[j]);
  *(u16x8*)(xconv + (size_t)bl * D_INNER + d) = o;
}

// ------------- B/C projection GEMM: xconv(8192x2048) @ Wt_bc^T(32x2048) ------
__global__ __launch_bounds__(256) void bc_gemm_k(const u16* __restrict__ xconv,
                                                 const u16* __restrict__ Wt,
                                                 float* __restrict__ partial){
  __shared__ __align__(16) u16 Asb[128*40];
  __shared__ __align__(16) u16 Wsb[32*40];
  const int kseg = blockIdx.x;
  const int m0   = blockIdx.y * 128;
  const int t    = threadIdx.x;
  const int wave = t >> 6, lane = t & 63;
  const int wm   = wave * 32;
  const int lrow = lane & 15, kq = (lane >> 4) * 8;

  f32x4 acc[2][2];
  #pragma unroll
  for (int i = 0; i < 2; ++i)
    #pragma unroll
    for (int j = 0; j < 2; ++j)
      acc[i][j] = (f32x4){0.f, 0.f, 0.f, 0.f};

  const int kbase = kseg * (D_INNER / KSEG);
  for (int ks = 0; ks < (D_INNER / KSEG); ks += 32) {
    int k0 = kbase + ks;
    #pragma unroll
    for (int i = 0; i < 2; ++i) {
      int f = (i*256 + t) * 8;
      int r = f >> 5, c = f & 31;
      *(u16x8*)&Asb[r*40 + c] = *(const u16x8*)&xconv[(size_t)(m0 + r)*D_INNER + k0 + c];
    }
    if (t < 128) {
      int f = t * 8;
      int r = f >> 5, c = f & 31;
      *(u16x8*)&Wsb[r*40 + c] = *(const u16x8*)&Wt[(size_t)r*D_INNER + k0 + c];
    }
    __syncthreads();
    s16x8 af[2], wf[2];
    #pragma unroll
    for (int i = 0; i < 2; ++i) af[i] = *(const s16x8*)&Asb[(wm + i*16 + lrow)*40 + kq];
    #pragma unroll
    for (int j = 0; j < 2; ++j) wf[j] = *(const s16x8*)&Wsb[(j*16 + lrow)*40 + kq];
    #pragma unroll
    for (int i = 0; i < 2; ++i)
      #pragma unroll
      for (int j = 0; j < 2; ++j)
        acc[i][j] = __builtin_amdgcn_mfma_f32_16x16x32_bf16(af[i], wf[j], acc[i][j], 0, 0, 0);
    __syncthreads();
  }

  #pragma unroll
  for (int i = 0; i < 2; ++i)
    #pragma unroll
    for (int j = 0; j < 2; ++j)
      #pragma unroll
      for (int r = 0; r < 4; ++r) {
        int row = m0 + wm + i*16 + (lane >> 4)*4 + r;
        int col = j*16 + lrow;
        partial[((size_t)kseg * ML + row) * 32 + col] = acc[i][j][r];
      }
}

// ------------- reduce partials + bias + mod -> Bbuf/Cbuf -------------
__global__ __launch_bounds__(256) void bc_reduce_k(const float* __restrict__ partial,
    const float* __restrict__ b_B, const float* __restrict__ B_mod,
    const float* __restrict__ b_C, const float* __restrict__ C_mod,
    float* __restrict__ Bbuf, float* __restrict__ Cbuf){
  int g = blockIdx.x * 256 + threadIdx.x;   // < ML*32
  int row = g >> 5, col = g & 31;
  int b = row >> 11;
  float s = 0.f;
  #pragma unroll
  for (int seg = 0; seg < KSEG; ++seg)
    s += partial[(size_t)seg * ML * 32 + g];
  if (col < 16) Bbuf[(size_t)row*16 + col]      = s + b_B[col]      + B_mod[b*16 + col];
  else          Cbuf[(size_t)row*16 + col - 16] = s + b_C[col - 16] + C_mod[b*16 + col - 16];
}

// ------------- chunked scan, pass 1: local chunk-final states -------------
__global__ __launch_bounds__(256) void state_k(const u16* __restrict__ xconv,
    const float* __restrict__ Bbuf, const float* __restrict__ A_log,
    float* __restrict__ hend){
  int c = blockIdx.x, db = blockIdx.y, b = blockIdx.z;
  int d = db*256 + threadIdx.x;

  float Abar[16];
  #pragma unroll
  for (int s = 0; s < 16; ++s)
    Abar[s] = __expf(-0.1f * __expf(A_log[d*16 + s]));
  float h[16];
  #pragma unroll
  for (int s = 0; s < 16; ++s) h[s] = 0.f;

  size_t base = (size_t)b * SEQ * D_INNER + (size_t)c * CH * D_INNER + d;
  const float* Br = Bbuf + ((size_t)b * SEQ + (size_t)c * CH) * 16;

  float Bc[16];
  #pragma unroll
  for (int s = 0; s < 16; ++s) Bc[s] = Br[s];
  float xn = b2f(xconv[base]);

  for (int l = 0; l < CH; ++l){
    float x = xn;
    float Bl[16];
    #pragma unroll
    for (int s = 0; s < 16; ++s) Bl[s] = Bc[s];
    if (l < CH-1){
      xn = b2f(xconv[base + (size_t)(l+1)*D_INNER]);
      #pragma unroll
      for (int s = 0; s < 16; ++s) Bc[s] = Br[(l+1)*16 + s];
    }
    #pragma unroll
    for (int s = 0; s < 16; ++s)
      h[s] = Abar[s]*h[s] + x*Bl[s];
  }
  float* hp = hend + (((size_t)(b*NCHUNK + c))*D_INNER + d)*16;
  #pragma unroll
  for (int q = 0; q < 4; ++q)
    *(f32x4*)(hp + q*4) = (f32x4){h[q*4], h[q*4+1], h[q*4+2], h[q*4+3]};
}

// ------------- chunked scan, pass 2: prefix across chunks -------------
__global__ __launch_bounds__(256) void prefix_k(const float* __restrict__ hend,
    const float* __restrict__ A_log, float* __restrict__ hin){
  int g = blockIdx.x*256 + threadIdx.x;
  int s = g & 15;
  int d = (g >> 4) & (D_INNER-1);
  int b = g >> 15;
  float decay = __expf(-0.1f * (float)CH * __expf(A_log[d*16 + s]));
  size_t stride = (size_t)D_INNER * 16;
  const float* he = hend + (size_t)b*NCHUNK*stride + (size_t)d*16 + s;
  float*       hi = hin  + (size_t)b*NCHUNK*stride + (size_t)d*16 + s;
  float h = 0.f;
  for (int c0 = 0; c0 < NCHUNK; c0 += 8){
    float v[8];
    #pragma unroll
    for (int i = 0; i < 8; ++i) v[i] = he[(size_t)(c0+i)*stride];
    #pragma unroll
    for (int i = 0; i < 8; ++i){
      hi[(size_t)(c0+i)*stride] = h;
      h = decay*h + v[i];
    }
  }
}

// ------------- chunked scan, pass 3: full scan per chunk from hin -------------
__global__ __launch_bounds__(256) void scan2_k(const u16* __restrict__ xconv,
    const u16* __restrict__ gate, const float* __restrict__ Bbuf, const float* __restrict__ Cbuf,
    const float* __restrict__ A_log, const float* __restrict__ Dp,
    const float* __restrict__ hin, u16* __restrict__ ybuf){
  int c = blockIdx.x, db = blockIdx.y, b = blockIdx.z;
  int d = db*256 + threadIdx.x;

  float Abar[16];
  #pragma unroll
  for (int s = 0; s < 16; ++s)
    Abar[s] = __expf(-0.1f * __expf(A_log[d*16 + s]));
  float h[16];
  const float* hp = hin + (((size_t)(b*NCHUNK + c))*D_INNER + d)*16;
  #pragma unroll
  for (int q = 0; q < 4; ++q){
    f32x4 v = *(const f32x4*)(hp + q*4);
    #pragma unroll
    for (int j = 0; j < 4; ++j) h[q*4 + j] = v[j];
  }
  float Dd = Dp[d];

  size_t base = (size_t)b * SEQ * D_INNER + (size_t)c * CH * D_INNER + d;
  const float* Br = Bbuf + ((size_t)b * SEQ + (size_t)c * CH) * 16;
  const float* Cr = Cbuf + ((size_t)b * SEQ + (size_t)c * CH) * 16;

  float Bc[16], Cc[16];
  #pragma unroll
  for (int s = 0; s < 16; ++s){ Bc[s] = Br[s]; Cc[s] = Cr[s]; }
  float xn = b2f(xconv[base]);
  float gn = b2f(gate[base]);

  for (int l = 0; l < CH; ++l){
    float x = xn, g = gn;
    float Bl[16], Cl[16];
    #pragma unroll
    for (int s = 0; s < 16; ++s){ Bl[s] = Bc[s]; Cl[s] = Cc[s]; }
    if (l < CH-1){
      size_t idx = base + (size_t)(l+1)*D_INNER;
      xn = b2f(xconv[idx]); gn = b2f(gate[idx]);
      #pragma unroll
      for (int s = 0; s < 16; ++s){ Bc[s] = Br[(l+1)*16 + s]; Cc[s] = Cr[(l+1)*16 + s]; }
    }
    float ya[4] = {0.f, 0.f, 0.f, 0.f};
    #pragma unroll
    for (int s = 0; s < 16; ++s){
      float hv = Abar[s]*h[s] + x*Bl[s];
      h[s] = hv;
      ya[s & 3] += hv * Cl[s];
    }
    float y = ((ya[0]+ya[1]) + (ya[2]+ya[3]) + Dd*x) * g;
    ybuf[base + (size_t)l*D_INNER] = f2b(y);
  }
}

extern "C" void kernel_launch(void* const* d_in, const int* in_sizes, int n_in,
                              void* d_out, int out_size, void* d_ws, size_t ws_size,
                              hipStream_t stream){
  const float* x      = (const float*)d_in[0];
  const float* B_mod  = (const float*)d_in[1];
  const float* C_mod  = (const float*)d_in[2];
  const float* W_in   = (const float*)d_in[3];
  const float* b_in   = (const float*)d_in[4];
  const float* conv_w = (const float*)d_in[5];
  const float* conv_b = (const float*)d_in[6];
  const float* A_log  = (const float*)d_in[7];
  const float* Dp     = (const float*)d_in[8];
  const float* W_B    = (const float*)d_in[9];
  const float* b_B    = (const float*)d_in[10];
  const float* W_C    = (const float*)d_in[11];
  const float* b_C    = (const float*)d_in[12];
  const float* W_out  = (const float*)d_in[13];
  const float* b_out  = (const float*)d_in[14];
  float* out = (float*)d_out;   // reference output dtype is float32

  char* ws = (char*)d_ws;
  size_t off = 0;
  auto alloc = [&](size_t bytes)->char* {
    char* p = ws + off; off += (bytes + 255) & ~(size_t)255; return p;
  };
  u16* Wt_in  = (u16*)alloc((size_t)(2*D_INNER)*D_MODEL*2); // 8.39 MB; dead after gemm1
  u16* Wt_out = (u16*)alloc((size_t)D_MODEL*D_INNER*2);     // 4.2 MB
  u16* xs     = (u16*)alloc((size_t)ML*D_INNER*2);          // x_ssm_silu; reused as y
  u16* gatep  = (u16*)alloc((size_t)ML*D_INNER*2);          // silu(x_res)
  u16* xconv  = (u16*)alloc((size_t)ML*D_INNER*2);
  float* Bbuf = (float*)alloc((size_t)ML*D_STATE*4);
  float* Cbuf = (float*)alloc((size_t)ML*D_STATE*4);
  u16* xbf    = (u16*)alloc((size_t)ML*D_MODEL*2);          // 16.8 MB; dead after gemm1
  float* hin  = (float*)alloc((size_t)BATCH*NCHUNK*D_INNER*16*4);
  u16* Wt_bc  = (u16*)alloc((size_t)32*D_INNER*2);          // 131 KB
  float* hend    = (float*)xbf;    // reuse: xbf dead before state_k
  float* partial = (float*)Wt_in;  // reuse: Wt_in dead after gemm1 (8.39 MB, exact)
  u16* ybuf = xs;                  // xs dead after conv/bc_gemm

  transpose_cast_k<<<dim3((2*D_INNER)/32, D_MODEL/32), 256, 0, stream>>>(W_in, Wt_in, D_MODEL, 2*D_INNER);
  transpose_cast_k<<<dim3(D_MODEL/32, D_INNER/32),     256, 0, stream>>>(W_out, Wt_out, D_INNER, D_MODEL);
  cast_k<<<dim3((ML*D_MODEL)/(256*8)), 256, 0, stream>>>(x, xbf);
  bc_wt_k<<<dim3(D_INNER/256, 32), 256, 0, stream>>>(W_B, W_C, Wt_bc);

  // gemm1: fragment-major 2-phase 256x256; 512 blocks x 512 threads; 2 n-blocks per XCD
  gemm1_k<<<dim3(512), 512, 0, stream>>>(xbf, Wt_in, b_in, xs, gatep);

  conv_k<<<dim3(ML), 256, 0, stream>>>(xs, conv_w, conv_b, xconv);

  bc_gemm_k<<<dim3(KSEG, ML/128), 256, 0, stream>>>(xconv, Wt_bc, partial);
  bc_reduce_k<<<dim3((ML*32)/256), 256, 0, stream>>>(
      partial, b_B, B_mod, b_C, C_mod, Bbuf, Cbuf);

  state_k<<<dim3(NCHUNK, D_INNER/256, BATCH), 256, 0, stream>>>(xconv, Bbuf, A_log, hend);
  prefix_k<<<dim3((BATCH*D_INNER*16)/256), 256, 0, stream>>>(hend, A_log, hin);
  scan2_k<<<dim3(NCHUNK, D_INNER/256, BATCH), 256, 0, stream>>>(
      xconv, gatep, Bbuf, Cbuf, A_log, Dp, hin, ybuf);

  // gemm2: N-blocks=8 -> 1 per XCD; 512 blocks total
  gemm_bt<0><<<dim3(512), 256, 0, stream>>>(
      ybuf, Wt_out, b_out, nullptr, nullptr, out, ML, D_MODEL, D_INNER, 1);
}

// Round 6
// 354.908 us; speedup vs baseline: 1.0701x; 1.0701x over previous
//
#include <hip/hip_runtime.h>
#include <stdint.h>

#define D_MODEL 1024
#define D_STATE 16
#define D_INNER 2048
#define BATCH   4
#define SEQ     2048
#define ML      (BATCH*SEQ)   // 8192 rows
#define CH      64
#define NCHUNK  (SEQ/CH)      // 32
#define KSEG    8             // K-split for B/C projection GEMM

typedef unsigned short u16;
typedef u16   u16x8  __attribute__((ext_vector_type(8)));
typedef short s16x8  __attribute__((ext_vector_type(8)));
typedef float f32x4  __attribute__((ext_vector_type(4)));

__device__ __forceinline__ float b2f(u16 u){
  union { uint32_t i; float f; } v; v.i = ((uint32_t)u) << 16; return v.f;
}
__device__ __forceinline__ u16 f2b(float f){
  uint32_t x = __float_as_uint(f);
  return (u16)((x + 0x7fffu + ((x >> 16) & 1u)) >> 16);   // RNE
}
__device__ __forceinline__ float silu_f(float v){
  return v / (1.f + __expf(-v));
}
// async global->LDS, 16 B per lane; lds base must be wave-uniform (lane i lands at base + i*16)
__device__ __forceinline__ void gl_lds16(const void* gp, void* lp){
  __builtin_amdgcn_global_load_lds(
      (const __attribute__((address_space(1))) void*)gp,
      (__attribute__((address_space(3))) void*)lp, 16, 0, 0);
}

// ------------- transpose + cast: in f32 (R x C) -> out bf16 (C x R) -------------
__global__ __launch_bounds__(256) void transpose_cast_k(const float* __restrict__ in,
                                                        u16* __restrict__ out,
                                                        int R, int C){
  __shared__ float tile[32][33];
  int bx = blockIdx.x * 32, by = blockIdx.y * 32;
  int tx = threadIdx.x & 31, ty = threadIdx.x >> 5;
  #pragma unroll
  for (int i = 0; i < 32; i += 8)
    tile[ty + i][tx] = in[(size_t)(by + ty + i) * C + bx + tx];
  __syncthreads();
  #pragma unroll
  for (int i = 0; i < 32; i += 8)
    out[(size_t)(bx + ty + i) * R + by + tx] = f2b(tile[tx][ty + i]);
}

// ------------- elementwise cast f32 -> bf16 (8 per thread) -------------
__global__ __launch_bounds__(256) void cast_k(const float* __restrict__ in,
                                              u16* __restrict__ out){
  size_t i = ((size_t)blockIdx.x * 256 + threadIdx.x) * 8;
  f32x4 a = *(const f32x4*)(in + i);
  f32x4 b = *(const f32x4*)(in + i + 4);
  u16x8 o;
  #pragma unroll
  for (int j = 0; j < 4; ++j){ o[j] = f2b(a[j]); o[4+j] = f2b(b[j]); }
  *(u16x8*)(out + i) = o;
}

// ------------- W_B|W_C (2048x16 f32 each) -> Wt_bc bf16 32x2048 -------------
__global__ __launch_bounds__(256) void bc_wt_k(const float* __restrict__ W_B,
                                               const float* __restrict__ W_C,
                                               u16* __restrict__ Wt){
  int n = blockIdx.y;                          // 0..31
  int k = blockIdx.x * 256 + threadIdx.x;      // 0..2047
  const float* src = (n < 16) ? W_B : W_C;
  Wt[(size_t)n * D_INNER + k] = f2b(src[(size_t)k * 16 + (n & 15)]);
}

// ================= 4-phase 256x256 GEMM for in_proj (full-line staging) =================
// M=8192, N=4096, K=1024. 512 threads = 8 waves (2M x 4N), per-wave output 128x64.
// R5 post-mortem: conflicts=0 and 2-vs-8 barriers both ~neutral; the remaining delta vs
// the proven m201 recipe is STAGING-REQUEST SHAPE. Old fragment-major staging issued
// 16 rows x 64B (16 scattered half-line L2 requests per gl_lds16). New layout is
// ROW-MAJOR halves [128][64] u16 with per-row chunk-XOR (c ^= row&7):
//  - gl_lds16 lane j -> row j>>3, chunk (j&7)^((j>>3)&7): the chunk SET per row is all 8
//    -> 8 rows x 128B FULL CACHE LINES per request.
//  - ds_read lane(lrow,q) col chunk (kk*4+q)^(lrow&7): involution matches the staged
//    permutation (row&7 == lrow&7 since frags are 16-row-aligned), and spreads the
//    wave across all 32 banks -> conflict-free (8 lanes per 16B slot-column = b128 min).
// Schedule = R4's verified 4-phase (best measured), unchanged.
// RACE RULES (R1): vmcnt drains only OWN DMAs -> cross-wave LDS reads sit after
// {all waves drained + s_barrier}. Ledger identical to R4.
#define G1_K  1024
#define G1_NT (G1_K/64)   // 16 K-tiles

__global__ __launch_bounds__(512, 2) void gemm1_k(const u16* __restrict__ A,
                                                  const u16* __restrict__ Bt,
                                                  const float* __restrict__ bias,
                                                  u16* __restrict__ out0,
                                                  u16* __restrict__ out1){
  __shared__ __align__(16) u16 ldsAll[256*264];  // 135168 B; staging uses first 128 KB,
  u16* ldsA = ldsAll;                            // epilogue reuses full array (pad 264)
  u16* ldsB = ldsAll + 4*8192;

  const int bid = blockIdx.x;
  const int xcd = bid & 7, t2 = bid >> 3;
  const int n0 = (xcd*2 + (t2 & 1)) * 256;     // 16 n-blocks, 2 per XCD
  const int m0 = (t2 >> 1) * 256;              // 32 m-blocks

  const int tid  = threadIdx.x;
  const int wave = tid >> 6, lane = tid & 63;
  const int wr = wave >> 2;                    // 0..1: M half
  const int wc = wave & 3;                     // 0..3: N quarter
  const int lrow = lane & 15;
  const int q    = lane >> 4;                  // 0..3

  // per-lane swizzled read cols (u16): kk=0 and kk=1; (c^4)*8 == c*8 ^ 32
  const int cx0  = ((q ^ (lrow & 7)) << 3);
  const int cx1  = cx0 ^ 32;
  const int arow = lrow * 64;

  // staging: one gl_lds16 = 8 rows x 128B (full lines), source col pre-swizzled
  const int srow = lane >> 3;                          // 0..7
  const int scol = (((lane & 7) ^ (lane >> 3)) << 3);  // swizzled 16B chunk

  auto stageA = [&](int buf, int h, int k0){
    const u16* s = A + (size_t)(m0 + h*128 + wave*16 + srow) * G1_K + k0 + scol;
    u16* d = ldsA + (buf*2 + h)*8192 + wave*1024;
    gl_lds16(s,                  d);        // rows wave*16 .. +7
    gl_lds16(s + (size_t)8*G1_K, d + 512);  // rows +8 .. +15
  };
  auto stageB = [&](int buf, int h, int k0){
    const u16* s = Bt + (size_t)(n0 + h*128 + wave*16 + srow) * G1_K + k0 + scol;
    u16* d = ldsB + (buf*2 + h)*8192 + wave*1024;
    gl_lds16(s,                  d);
    gl_lds16(s + (size_t)8*G1_K, d + 512);
  };

  f32x4 acc[8][4];
  #pragma unroll
  for (int i = 0; i < 8; ++i)
    #pragma unroll
    for (int j = 0; j < 4; ++j) acc[i][j] = (f32x4){0.f,0.f,0.f,0.f};

  s16x8 aA[2][2], aB[2][2];       // alternating A-quadrant frags
  s16x8 bX[4][2], bY[4][2];       // alternating per-tile B frags

  // frag (mi,kk) of A half wr, buf nb: ldsA + (nb*2+wr)*8192 + mi*1024 + arow + cx{kk}
  #define READ_AQ(dst, Q, nb)                                            \
    { const u16* p_ = ldsA + ((nb)*2 + wr)*8192 + (Q)*2048 + arow;       \
      dst[0][0] = *(const s16x8*)(p_ + cx0);                             \
      dst[0][1] = *(const s16x8*)(p_ + cx1);                             \
      dst[1][0] = *(const s16x8*)(p_ + 1024 + cx0);                      \
      dst[1][1] = *(const s16x8*)(p_ + 1024 + cx1); }
  #define READ_B8(dst, nb)                                               \
    { const u16* p_ = ldsB + ((nb)*2 + (wc>>1))*8192 + (wc&1)*4096 + arow; \
      _Pragma("unroll")                                                  \
      for (int nj_ = 0; nj_ < 4; ++nj_){                                 \
        dst[nj_][0] = *(const s16x8*)(p_ + nj_*1024 + cx0);              \
        dst[nj_][1] = *(const s16x8*)(p_ + nj_*1024 + cx1); } }
  #define MFMA_Q(Q, AF, BF)                                              \
    { _Pragma("unroll")                                                  \
      for (int nj_ = 0; nj_ < 4; ++nj_){                                 \
        _Pragma("unroll")                                                \
        for (int kk_ = 0; kk_ < 2; ++kk_){                               \
          acc[2*(Q)][nj_]   = __builtin_amdgcn_mfma_f32_16x16x32_bf16(AF[0][kk_], BF[nj_][kk_], acc[2*(Q)][nj_],   0,0,0); \
          acc[2*(Q)+1][nj_] = __builtin_amdgcn_mfma_f32_16x16x32_bf16(AF[1][kk_], BF[nj_][kk_], acc[2*(Q)+1][nj_], 0,0,0); } } }

  // ---- prologue: stage tile0 + B(t1); drain tile0; BARRIER; then cross-wave reads ----
  stageA(0,0,0); stageA(0,1,0); stageB(0,0,0); stageB(0,1,0);
  stageB(1,0,64); stageB(1,1,64);
  asm volatile("s_waitcnt vmcnt(4)" ::: "memory");   // own tile0 DMAs done; B(t1) in flight
  __builtin_amdgcn_s_barrier();                       // ALL waves' tile0 DMAs visible
  __builtin_amdgcn_sched_barrier(0);                  // pin reads below the barrier
  READ_B8(bX, 0);
  READ_AQ(aA, 0, 0);

  auto tile_body = [&](int tt, int buf, s16x8 (&bC)[4][2], s16x8 (&bN)[4][2]){
    const int k1 = (tt+1 < G1_NT ? tt+1 : G1_NT-1) * 64;   // clamped: junk restage, never read
    const int k2 = (tt+2 < G1_NT ? tt+2 : G1_NT-1) * 64;
    const int nb = buf ^ 1;

    // ---- p0: read Q1 -> aB; stage A(t+1); MFMA Q0 ----
    READ_AQ(aB, 1, buf);
    stageA(nb, 1, k1);
    stageA(nb, 0, k1);
    __builtin_amdgcn_s_barrier();
    asm volatile("s_waitcnt lgkmcnt(4)" ::: "memory");   // drains p3's 12; Q1 stays out
    __builtin_amdgcn_sched_barrier(0);
    __builtin_amdgcn_s_setprio(1);
    MFMA_Q(0, aA, bC);
    __builtin_amdgcn_s_setprio(0);
    __builtin_amdgcn_s_barrier();

    // ---- p1: read Q2 -> aA; stage B0(t+2); MFMA Q1 ----
    READ_AQ(aA, 2, buf);
    stageB(buf, 0, k2);
    __builtin_amdgcn_s_barrier();
    asm volatile("s_waitcnt lgkmcnt(4)" ::: "memory");   // drains Q1; Q2 stays out
    __builtin_amdgcn_sched_barrier(0);
    __builtin_amdgcn_s_setprio(1);
    MFMA_Q(1, aB, bC);
    __builtin_amdgcn_s_setprio(0);
    __builtin_amdgcn_s_barrier();

    // ---- p2: read Q3 -> aB; stage B1(t+2); MFMA Q2 ----
    READ_AQ(aB, 3, buf);
    stageB(buf, 1, k2);
    __builtin_amdgcn_s_barrier();
    asm volatile("s_waitcnt lgkmcnt(4)" ::: "memory");   // drains Q2; Q3 stays out
    __builtin_amdgcn_sched_barrier(0);
    __builtin_amdgcn_s_setprio(1);
    MFMA_Q(2, aA, bC);
    __builtin_amdgcn_s_setprio(0);
    __builtin_amdgcn_s_barrier();

    // ---- p3: drain tile t+1 DMAs; BARRIER; cross-wave reads of t+1; MFMA Q3 ----
    asm volatile("s_waitcnt vmcnt(4)" ::: "memory");   // B(t+1)+A(t+1) done; B(t+2) out
    __builtin_amdgcn_s_barrier();                      // all waves' t+1 DMAs visible
    __builtin_amdgcn_sched_barrier(0);                 // pin reads below the barrier
    READ_B8(bN, nb);
    READ_AQ(aA, 0, nb);
    asm volatile("s_waitcnt lgkmcnt(12)" ::: "memory"); // drains Q3; 12 new reads stay out
    __builtin_amdgcn_sched_barrier(0);
    __builtin_amdgcn_s_setprio(1);
    MFMA_Q(3, aB, bC);
    __builtin_amdgcn_s_setprio(0);
    __builtin_amdgcn_s_barrier();
  };

  for (int tt2 = 0; tt2 < G1_NT; tt2 += 2) {
    tile_body(tt2,     0, bX, bY);
    tile_body(tt2 + 1, 1, bY, bX);
  }

  // ---- epilogue: drain junk DMA, restage C through LDS (pad 264), coalesced stores ----
  asm volatile("s_waitcnt vmcnt(0)" ::: "memory");
  __syncthreads();

  #pragma unroll
  for (int nj = 0; nj < 4; ++nj) {
    const int colg = n0 + wc*64 + nj*16 + lrow;
    const float bv = bias[colg];
    const int coll = wc*64 + nj*16 + lrow;
    #pragma unroll
    for (int mi = 0; mi < 8; ++mi) {
      #pragma unroll
      for (int r = 0; r < 4; ++r) {
        const int rowl = wr*128 + mi*16 + q*4 + r;   // C/D: col=lane&15, row=quad*4+reg
        ldsAll[rowl*264 + coll] = f2b(silu_f(acc[mi][nj][r] + bv));
      }
    }
  }
  __syncthreads();

  u16* op = (n0 < D_INNER) ? out0 : out1;
  const int colbase = n0 & (D_INNER - 1);
  #pragma unroll
  for (int it = 0; it < 16; ++it) {
    const int f   = it*512 + tid;
    const int row = f >> 5;           // 0..255
    const int ch  = f & 31;           // 16B chunk within 512B row-span
    u16x8 v = *(const u16x8*)(ldsAll + row*264 + ch*8);
    *(u16x8*)(op + (size_t)(m0 + row)*D_INNER + colbase + ch*8) = v;
  }
  #undef READ_AQ
  #undef READ_B8
  #undef MFMA_Q
}

// ------------- MFMA GEMM, double-buffered DMA, 1 barrier/iter (kept for gemm2) -------------
// MODE 0: outf[row*N+col] = f32(acc + bias[col])          (final output, f32)
template<int MODE>
__global__ __launch_bounds__(256) void gemm_bt(const u16* __restrict__ A,
                                               const u16* __restrict__ Bt,
                                               const float* __restrict__ bias,
                                               u16* __restrict__ out0,
                                               u16* __restrict__ out1,
                                               float* __restrict__ outf,
                                               int M, int N, int K, int n_per_xcd){
  __shared__ __align__(16) u16 Asb[2][128*32];   // unpadded: DMA layout constraint
  __shared__ __align__(16) u16 Bsb[2][128*32];
  const int bid = blockIdx.x;
  const int xcd = bid & 7, t2 = bid >> 3;
  const int n0 = (xcd * n_per_xcd + (t2 % n_per_xcd)) * 128;
  const int m0 = (t2 / n_per_xcd) * 128;
  const int t    = threadIdx.x;
  const int wave = t >> 6, lane = t & 63;
  const int wm   = (wave >> 1) * 64, wn = (wave & 1) * 64;
  const int lrow = lane & 15, kq = (lane >> 4) * 8;
  const int srow = lane >> 2;            // staging: row within 16-row block
  const int scol = (lane & 3) * 8;       // staging: 8-u16 chunk within row

  f32x4 acc[4][4];
  #pragma unroll
  for (int i = 0; i < 4; ++i)
    #pragma unroll
    for (int j = 0; j < 4; ++j)
      acc[i][j] = (f32x4){0.f, 0.f, 0.f, 0.f};

  auto stage = [&](int buf, int k0){
    #pragma unroll
    for (int i = 0; i < 2; ++i) {
      int R0 = (wave*2 + i) * 16;        // 0,16,...,112
      gl_lds16(&A [(size_t)(m0 + R0 + srow)*K + k0 + scol], &Asb[buf][R0*32]);
      gl_lds16(&Bt[(size_t)(n0 + R0 + srow)*K + k0 + scol], &Bsb[buf][R0*32]);
    }
  };

  const int KT = K >> 5;
  stage(0, 0);
  __syncthreads();
  for (int kt = 0; kt < KT; ++kt) {
    const int cur = kt & 1;
    if (kt + 1 < KT) stage(1 - cur, (kt + 1) * 32);   // prefetch overlaps compute below
    s16x8 af[4], bfr[4];
    #pragma unroll
    for (int i = 0; i < 4; ++i) af[i]  = *(const s16x8*)&Asb[cur][(wm + i*16 + lrow)*32 + kq];
    #pragma unroll
    for (int j = 0; j < 4; ++j) bfr[j] = *(const s16x8*)&Bsb[cur][(wn + j*16 + lrow)*32 + kq];
    #pragma unroll
    for (int i = 0; i < 4; ++i)
      #pragma unroll
      for (int j = 0; j < 4; ++j)
        acc[i][j] = __builtin_amdgcn_mfma_f32_16x16x32_bf16(af[i], bfr[j], acc[i][j], 0, 0, 0);
    __syncthreads();   // drains prefetch DMA + protects cur buffer reuse
  }

  const int Nh = N >> 1;
  #pragma unroll
  for (int i = 0; i < 4; ++i) {
    #pragma unroll
    for (int j = 0; j < 4; ++j) {
      int col = n0 + wn + j*16 + lrow;
      float bv = bias[col];
      #pragma unroll
      for (int r = 0; r < 4; ++r) {
        int row = m0 + wm + i*16 + (lane >> 4)*4 + r;   // C/D: col=lane&15, row=quad*4+reg
        float v = acc[i][j][r] + bv;
        if (MODE == 0) {
          outf[(size_t)row * N + col] = v;
        } else {
          float s = silu_f(v);
          if (col < Nh) out0[(size_t)row * Nh + col]        = f2b(s);
          else          out1[(size_t)row * Nh + (col - Nh)] = f2b(s);
        }
      }
    }
  }
}

// ------------- depthwise conv(3) only -------------
__global__ __launch_bounds__(256) void conv_k(const u16* __restrict__ xs,
    const float* __restrict__ conv_w, const float* __restrict__ conv_b,
    u16* __restrict__ xconv){
  int bl = blockIdx.x;
  int l = bl & (SEQ-1);
  int d = threadIdx.x * 8;
  const u16* row0 = xs + (size_t)bl * D_INNER + d;

  float f0[8], fm[8], fp[8];
  { u16x8 v = *(const u16x8*)row0;
    #pragma unroll
    for (int j = 0; j < 8; ++j) f0[j] = b2f(v[j]); }
  if (l > 0) {
    u16x8 v = *(const u16x8*)(row0 - D_INNER);
    #pragma unroll
    for (int j = 0; j < 8; ++j) fm[j] = b2f(v[j]);
  } else {
    #pragma unroll
    for (int j = 0; j < 8; ++j) fm[j] = 0.f;
  }
  if (l < SEQ-1) {
    u16x8 v = *(const u16x8*)(row0 + D_INNER);
    #pragma unroll
    for (int j = 0; j < 8; ++j) fp[j] = b2f(v[j]);
  } else {
    #pragma unroll
    for (int j = 0; j < 8; ++j) fp[j] = 0.f;
  }

  const float* wp = conv_w + (size_t)d * 3;
  float wl[24];
  #pragma unroll
  for (int q = 0; q < 6; ++q){
    f32x4 v = *(const f32x4*)(wp + q*4);
    #pragma unroll
    for (int j = 0; j < 4; ++j) wl[q*4 + j] = v[j];
  }
  float cb[8];
  { f32x4 c0 = *(const f32x4*)(conv_b + d), c1 = *(const f32x4*)(conv_b + d + 4);
    #pragma unroll
    for (int j = 0; j < 4; ++j){ cb[j] = c0[j]; cb[4+j] = c1[j]; } }

  u16x8 o;
  #pragma unroll
  for (int j = 0; j < 8; ++j)
    o[j] = f2b(wl[3*j]*fm[j] + wl[3*j+1]*f0[j] + wl[3*j+2]*fp[j] + cb[j]);
  *(u16x8*)(xconv + (size_t)bl * D_INNER + d) = o;
}

// ------------- B/C projection GEMM: xconv(8192x2048) @ Wt_bc^T(32x2048) ------
__global__ __launch_bounds__(256) void bc_gemm_k(const u16* __restrict__ xconv,
                                                 const u16* __restrict__ Wt,
                                                 float* __restrict__ partial){
  __shared__ __align__(16) u16 Asb[128*40];
  __shared__ __align__(16) u16 Wsb[32*40];
  const int kseg = blockIdx.x;
  const int m0   = blockIdx.y * 128;
  const int t    = threadIdx.x;
  const int wave = t >> 6, lane = t & 63;
  const int wm   = wave * 32;
  const int lrow = lane & 15, kq = (lane >> 4) * 8;

  f32x4 acc[2][2];
  #pragma unroll
  for (int i = 0; i < 2; ++i)
    #pragma unroll
    for (int j = 0; j < 2; ++j)
      acc[i][j] = (f32x4){0.f, 0.f, 0.f, 0.f};

  const int kbase = kseg * (D_INNER / KSEG);
  for (int ks = 0; ks < (D_INNER / KSEG); ks += 32) {
    int k0 = kbase + ks;
    #pragma unroll
    for (int i = 0; i < 2; ++i) {
      int f = (i*256 + t) * 8;
      int r = f >> 5, c = f & 31;
      *(u16x8*)&Asb[r*40 + c] = *(const u16x8*)&xconv[(size_t)(m0 + r)*D_INNER + k0 + c];
    }
    if (t < 128) {
      int f = t * 8;
      int r = f >> 5, c = f & 31;
      *(u16x8*)&Wsb[r*40 + c] = *(const u16x8*)&Wt[(size_t)r*D_INNER + k0 + c];
    }
    __syncthreads();
    s16x8 af[2], wf[2];
    #pragma unroll
    for (int i = 0; i < 2; ++i) af[i] = *(const s16x8*)&Asb[(wm + i*16 + lrow)*40 + kq];
    #pragma unroll
    for (int j = 0; j < 2; ++j) wf[j] = *(const s16x8*)&Wsb[(j*16 + lrow)*40 + kq];
    #pragma unroll
    for (int i = 0; i < 2; ++i)
      #pragma unroll
      for (int j = 0; j < 2; ++j)
        acc[i][j] = __builtin_amdgcn_mfma_f32_16x16x32_bf16(af[i], wf[j], acc[i][j], 0, 0, 0);
    __syncthreads();
  }

  #pragma unroll
  for (int i = 0; i < 2; ++i)
    #pragma unroll
    for (int j = 0; j < 2; ++j)
      #pragma unroll
      for (int r = 0; r < 4; ++r) {
        int row = m0 + wm + i*16 + (lane >> 4)*4 + r;
        int col = j*16 + lrow;
        partial[((size_t)kseg * ML + row) * 32 + col] = acc[i][j][r];
      }
}

// ------------- reduce partials + bias + mod -> Bbuf/Cbuf -------------
__global__ __launch_bounds__(256) void bc_reduce_k(const float* __restrict__ partial,
    const float* __restrict__ b_B, const float* __restrict__ B_mod,
    const float* __restrict__ b_C, const float* __restrict__ C_mod,
    float* __restrict__ Bbuf, float* __restrict__ Cbuf){
  int g = blockIdx.x * 256 + threadIdx.x;   // < ML*32
  int row = g >> 5, col = g & 31;
  int b = row >> 11;
  float s = 0.f;
  #pragma unroll
  for (int seg = 0; seg < KSEG; ++seg)
    s += partial[(size_t)seg * ML * 32 + g];
  if (col < 16) Bbuf[(size_t)row*16 + col]      = s + b_B[col]      + B_mod[b*16 + col];
  else          Cbuf[(size_t)row*16 + col - 16] = s + b_C[col - 16] + C_mod[b*16 + col - 16];
}

// ------------- chunked scan, pass 1: local chunk-final states -------------
__global__ __launch_bounds__(256) void state_k(const u16* __restrict__ xconv,
    const float* __restrict__ Bbuf, const float* __restrict__ A_log,
    float* __restrict__ hend){
  int c = blockIdx.x, db = blockIdx.y, b = blockIdx.z;
  int d = db*256 + threadIdx.x;

  float Abar[16];
  #pragma unroll
  for (int s = 0; s < 16; ++s)
    Abar[s] = __expf(-0.1f * __expf(A_log[d*16 + s]));
  float h[16];
  #pragma unroll
  for (int s = 0; s < 16; ++s) h[s] = 0.f;

  size_t base = (size_t)b * SEQ * D_INNER + (size_t)c * CH * D_INNER + d;
  const float* Br = Bbuf + ((size_t)b * SEQ + (size_t)c * CH) * 16;

  float Bc[16];
  #pragma unroll
  for (int s = 0; s < 16; ++s) Bc[s] = Br[s];
  float xn = b2f(xconv[base]);

  for (int l = 0; l < CH; ++l){
    float x = xn;
    float Bl[16];
    #pragma unroll
    for (int s = 0; s < 16; ++s) Bl[s] = Bc[s];
    if (l < CH-1){
      xn = b2f(xconv[base + (size_t)(l+1)*D_INNER]);
      #pragma unroll
      for (int s = 0; s < 16; ++s) Bc[s] = Br[(l+1)*16 + s];
    }
    #pragma unroll
    for (int s = 0; s < 16; ++s)
      h[s] = Abar[s]*h[s] + x*Bl[s];
  }
  float* hp = hend + (((size_t)(b*NCHUNK + c))*D_INNER + d)*16;
  #pragma unroll
  for (int q = 0; q < 4; ++q)
    *(f32x4*)(hp + q*4) = (f32x4){h[q*4], h[q*4+1], h[q*4+2], h[q*4+3]};
}

// ------------- chunked scan, pass 2: prefix across chunks -------------
__global__ __launch_bounds__(256) void prefix_k(const float* __restrict__ hend,
    const float* __restrict__ A_log, float* __restrict__ hin){
  int g = blockIdx.x*256 + threadIdx.x;
  int s = g & 15;
  int d = (g >> 4) & (D_INNER-1);
  int b = g >> 15;
  float decay = __expf(-0.1f * (float)CH * __expf(A_log[d*16 + s]));
  size_t stride = (size_t)D_INNER * 16;
  const float* he = hend + (size_t)b*NCHUNK*stride + (size_t)d*16 + s;
  float*       hi = hin  + (size_t)b*NCHUNK*stride + (size_t)d*16 + s;
  float h = 0.f;
  for (int c0 = 0; c0 < NCHUNK; c0 += 8){
    float v[8];
    #pragma unroll
    for (int i = 0; i < 8; ++i) v[i] = he[(size_t)(c0+i)*stride];
    #pragma unroll
    for (int i = 0; i < 8; ++i){
      hi[(size_t)(c0+i)*stride] = h;
      h = decay*h + v[i];
    }
  }
}

// ------------- chunked scan, pass 3: full scan per chunk from hin -------------
__global__ __launch_bounds__(256) void scan2_k(const u16* __restrict__ xconv,
    const u16* __restrict__ gate, const float* __restrict__ Bbuf, const float* __restrict__ Cbuf,
    const float* __restrict__ A_log, const float* __restrict__ Dp,
    const float* __restrict__ hin, u16* __restrict__ ybuf){
  int c = blockIdx.x, db = blockIdx.y, b = blockIdx.z;
  int d = db*256 + threadIdx.x;

  float Abar[16];
  #pragma unroll
  for (int s = 0; s < 16; ++s)
    Abar[s] = __expf(-0.1f * __expf(A_log[d*16 + s]));
  float h[16];
  const float* hp = hin + (((size_t)(b*NCHUNK + c))*D_INNER + d)*16;
  #pragma unroll
  for (int q = 0; q < 4; ++q){
    f32x4 v = *(const f32x4*)(hp + q*4);
    #pragma unroll
    for (int j = 0; j < 4; ++j) h[q*4 + j] = v[j];
  }
  float Dd = Dp[d];

  size_t base = (size_t)b * SEQ * D_INNER + (size_t)c * CH * D_INNER + d;
  const float* Br = Bbuf + ((size_t)b * SEQ + (size_t)c * CH) * 16;
  const float* Cr = Cbuf + ((size_t)b * SEQ + (size_t)c * CH) * 16;

  float Bc[16], Cc[16];
  #pragma unroll
  for (int s = 0; s < 16; ++s){ Bc[s] = Br[s]; Cc[s] = Cr[s]; }
  float xn = b2f(xconv[base]);
  float gn = b2f(gate[base]);

  for (int l = 0; l < CH; ++l){
    float x = xn, g = gn;
    float Bl[16], Cl[16];
    #pragma unroll
    for (int s = 0; s < 16; ++s){ Bl[s] = Bc[s]; Cl[s] = Cc[s]; }
    if (l < CH-1){
      size_t idx = base + (size_t)(l+1)*D_INNER;
      xn = b2f(xconv[idx]); gn = b2f(gate[idx]);
      #pragma unroll
      for (int s = 0; s < 16; ++s){ Bc[s] = Br[(l+1)*16 + s]; Cc[s] = Cr[(l+1)*16 + s]; }
    }
    float ya[4] = {0.f, 0.f, 0.f, 0.f};
    #pragma unroll
    for (int s = 0; s < 16; ++s){
      float hv = Abar[s]*h[s] + x*Bl[s];
      h[s] = hv;
      ya[s & 3] += hv * Cl[s];
    }
    float y = ((ya[0]+ya[1]) + (ya[2]+ya[3]) + Dd*x) * g;
    ybuf[base + (size_t)l*D_INNER] = f2b(y);
  }
}

extern "C" void kernel_launch(void* const* d_in, const int* in_sizes, int n_in,
                              void* d_out, int out_size, void* d_ws, size_t ws_size,
                              hipStream_t stream){
  const float* x      = (const float*)d_in[0];
  const float* B_mod  = (const float*)d_in[1];
  const float* C_mod  = (const float*)d_in[2];
  const float* W_in   = (const float*)d_in[3];
  const float* b_in   = (const float*)d_in[4];
  const float* conv_w = (const float*)d_in[5];
  const float* conv_b = (const float*)d_in[6];
  const float* A_log  = (const float*)d_in[7];
  const float* Dp     = (const float*)d_in[8];
  const float* W_B    = (const float*)d_in[9];
  const float* b_B    = (const float*)d_in[10];
  const float* W_C    = (const float*)d_in[11];
  const float* b_C    = (const float*)d_in[12];
  const float* W_out  = (const float*)d_in[13];
  const float* b_out  = (const float*)d_in[14];
  float* out = (float*)d_out;   // reference output dtype is float32

  char* ws = (char*)d_ws;
  size_t off = 0;
  auto alloc = [&](size_t bytes)->char* {
    char* p = ws + off; off += (bytes + 255) & ~(size_t)255; return p;
  };
  u16* Wt_in  = (u16*)alloc((size_t)(2*D_INNER)*D_MODEL*2); // 8.39 MB; dead after gemm1
  u16* Wt_out = (u16*)alloc((size_t)D_MODEL*D_INNER*2);     // 4.2 MB
  u16* xs     = (u16*)alloc((size_t)ML*D_INNER*2);          // x_ssm_silu; reused as y
  u16* gatep  = (u16*)alloc((size_t)ML*D_INNER*2);          // silu(x_res)
  u16* xconv  = (u16*)alloc((size_t)ML*D_INNER*2);
  float* Bbuf = (float*)alloc((size_t)ML*D_STATE*4);
  float* Cbuf = (float*)alloc((size_t)ML*D_STATE*4);
  u16* xbf    = (u16*)alloc((size_t)ML*D_MODEL*2);          // 16.8 MB; dead after gemm1
  float* hin  = (float*)alloc((size_t)BATCH*NCHUNK*D_INNER*16*4);
  u16* Wt_bc  = (u16*)alloc((size_t)32*D_INNER*2);          // 131 KB
  float* hend    = (float*)xbf;    // reuse: xbf dead before state_k
  float* partial = (float*)Wt_in;  // reuse: Wt_in dead after gemm1 (8.39 MB, exact)
  u16* ybuf = xs;                  // xs dead after conv/bc_gemm

  transpose_cast_k<<<dim3((2*D_INNER)/32, D_MODEL/32), 256, 0, stream>>>(W_in, Wt_in, D_MODEL, 2*D_INNER);
  transpose_cast_k<<<dim3(D_MODEL/32, D_INNER/32),     256, 0, stream>>>(W_out, Wt_out, D_INNER, D_MODEL);
  cast_k<<<dim3((ML*D_MODEL)/(256*8)), 256, 0, stream>>>(x, xbf);
  bc_wt_k<<<dim3(D_INNER/256, 32), 256, 0, stream>>>(W_B, W_C, Wt_bc);

  // gemm1: full-line-staging 4-phase 256x256; 512 blocks x 512 threads; 2 n-blocks per XCD
  gemm1_k<<<dim3(512), 512, 0, stream>>>(xbf, Wt_in, b_in, xs, gatep);

  conv_k<<<dim3(ML), 256, 0, stream>>>(xs, conv_w, conv_b, xconv);

  bc_gemm_k<<<dim3(KSEG, ML/128), 256, 0, stream>>>(xconv, Wt_bc, partial);
  bc_reduce_k<<<dim3((ML*32)/256), 256, 0, stream>>>(
      partial, b_B, B_mod, b_C, C_mod, Bbuf, Cbuf);

  state_k<<<dim3(NCHUNK, D_INNER/256, BATCH), 256, 0, stream>>>(xconv, Bbuf, A_log, hend);
  prefix_k<<<dim3((BATCH*D_INNER*16)/256), 256, 0, stream>>>(hend, A_log, hin);
  scan2_k<<<dim3(NCHUNK, D_INNER/256, BATCH), 256, 0, stream>>>(
      xconv, gatep, Bbuf, Cbuf, A_log, Dp, hin, ybuf);

  // gemm2: N-blocks=8 -> 1 per XCD; 512 blocks total
  gemm_bt<0><<<dim3(512), 256, 0, stream>>>(
      ybuf, Wt_out, b_out, nullptr, nullptr, out, ML, D_MODEL, D_INNER, 1);
}